// Round 3
// baseline (29.935 us; speedup 1.0000x reference)
//
#include <hip/hip_runtime.h>

// Problem constants (match reference): B=128, T=512, DZ=512
#define BB 128
#define TT 512
#define DZ 512
#define RPB 32                          // rows (b,t pairs) per block
#define NBLOCKS ((BB * TT) / RPB)       // 2048 blocks -> 8 per CU
// out[b,t,d] = init[b,d] + f[d] * prefixsum_{s<=t}(x[b,s])

typedef float f4_t __attribute__((ext_vector_type(4)));

// Store 16 rows of parity H. v[] indices fold to constants after unroll;
// readlane index (lbase + const) is block-uniform -> SGPR broadcast, so the
// FMA consumes the scan value as a scalar operand. No LDS, no barriers.
template<int H>
__device__ __forceinline__ void store_rows(const float v[8], int lbase,
                                           const f4_t f4, const f4_t i4,
                                           float* outp) {
#pragma unroll
    for (int iter = 0; iter < RPB / 2; ++iter) {
        const int toff = 2 * iter + H;                 // compile-time
        const float st = __int_as_float(__builtin_amdgcn_readlane(
            __float_as_int(v[toff & 7]), lbase + (toff >> 3)));
        f4_t o;
        o.x = i4.x + f4.x * st;
        o.y = i4.y + f4.y * st;
        o.z = i4.z + f4.z * st;
        o.w = i4.w + f4.w * st;
        __builtin_nontemporal_store(o, reinterpret_cast<f4_t*>(outp));
        outp += 2 * DZ;
    }
}

__global__ __launch_bounds__(256, 8) void lts_kernel(
    const float* __restrict__ t_in,   // (B, T)
    const float* __restrict__ init,   // (B, DZ)
    const float* __restrict__ f,      // (DZ)
    float* __restrict__ out)          // (B, T, DZ)
{
    const int tid  = threadIdx.x;                // 0..255
    const int lane = tid & 63;
    const int g0   = blockIdx.x * RPB;           // global row base (b*T + t0)
    const int b    = g0 >> 9;                    // batch (T = 512)
    const int t0   = g0 & (TT - 1);              // local time base (mult of 32)

    // ---- Every wave redundantly computes the full inclusive scan of
    //      t_in[b, :] in registers: lane l holds s[l*8 .. l*8+7]. ----
    const float* xb = t_in + b * TT + lane * 8;
    const f4_t a = *reinterpret_cast<const f4_t*>(xb);
    const f4_t c = *reinterpret_cast<const f4_t*>(xb + 4);
    float v[8];
    v[0] = a.x;        v[1] = v[0] + a.y;
    v[2] = v[1] + a.z; v[3] = v[2] + a.w;
    v[4] = v[3] + c.x; v[5] = v[4] + c.y;
    v[6] = v[5] + c.z; v[7] = v[6] + c.w;
    float run = v[7];
#pragma unroll
    for (int off = 1; off < 64; off <<= 1) {
        const float y = __shfl_up(run, off, 64);
        if (lane >= off) run += y;
    }
    const float excl = run - v[7];               // exclusive prefix of lane totals
#pragma unroll
    for (int k = 0; k < 8; ++k) v[k] += excl;

    // ---- Fixed float4 column per thread across the full 512-float row ----
    const int q = tid & 127;                     // float4 column, 0..127
    const int h = tid >> 7;                      // wave-pair parity (uniform)
    const int d = q * 4;

    const f4_t f4 = *reinterpret_cast<const f4_t*>(&f[d]);
    const f4_t i4 = *reinterpret_cast<const f4_t*>(&init[b * DZ + d]);

    float* outp = out + ((size_t)(g0 + h) * DZ + d);
    const int lbase = t0 >> 3;                   // lane holding s[t0]

    if (h == 0) store_rows<0>(v, lbase, f4, i4, outp);
    else        store_rows<1>(v, lbase, f4, i4, outp);
}

extern "C" void kernel_launch(void* const* d_in, const int* in_sizes, int n_in,
                              void* d_out, int out_size, void* d_ws, size_t ws_size,
                              hipStream_t stream) {
    const float* t_in = (const float*)d_in[0];  // (B,T,1) -> (B,T)
    const float* init = (const float*)d_in[1];  // (B,DZ)
    const float* f    = (const float*)d_in[2];  // (1,DZ) -> (DZ)
    float* out        = (float*)d_out;          // (B,T,DZ)

    lts_kernel<<<dim3(NBLOCKS), dim3(256), 0, stream>>>(t_in, init, f, out);
}

// Round 4
// 26.270 us; speedup vs baseline: 1.1395x; 1.1395x over previous
//
#include <hip/hip_runtime.h>

// Problem constants (match reference): B=128, T=512, DZ=512
#define BB 128
#define TT 512
#define DZ 512
#define RPB 128                         // rows (b,t pairs) per block
#define NBLOCKS ((BB * TT) / RPB)       // 512 blocks -> 2 per CU
// out[b,t,d] = init[b,d] + f[d] * prefixsum_{s<=t}(x[b,s])

typedef float f4_t __attribute__((ext_vector_type(4)));

__global__ __launch_bounds__(256, 4) void lts_kernel(
    const float* __restrict__ t_in,   // (B, T)
    const float* __restrict__ init,   // (B, DZ)
    const float* __restrict__ f,      // (DZ)
    float* __restrict__ out)          // (B, T, DZ)
{
    __shared__ float s[TT];

    const int tid = threadIdx.x;                 // 0..255
    const int g0  = blockIdx.x * RPB;            // global row base (b*T + t0)
    const int b   = g0 >> 9;                     // batch (T = 512)
    const int t0  = g0 & (TT - 1);               // local time base (mult of 128)

    // ---- Prologue: wave 0 computes the full inclusive scan of t_in[b, :] ----
    if (tid < 64) {
        const float* xb = t_in + b * TT + tid * 8;
        const f4_t a = *reinterpret_cast<const f4_t*>(xb);
        const f4_t c = *reinterpret_cast<const f4_t*>(xb + 4);
        const float v0 = a.x;
        const float v1 = v0 + a.y;
        const float v2 = v1 + a.z;
        const float v3 = v2 + a.w;
        const float v4 = v3 + c.x;
        const float v5 = v4 + c.y;
        const float v6 = v5 + c.z;
        const float v7 = v6 + c.w;
        float run = v7;
#pragma unroll
        for (int off = 1; off < 64; off <<= 1) {
            const float y = __shfl_up(run, off, 64);
            if (tid >= off) run += y;
        }
        const float excl = run - v7;             // exclusive prefix of lane totals
        f4_t o0, o1;
        o0.x = v0 + excl; o0.y = v1 + excl; o0.z = v2 + excl; o0.w = v3 + excl;
        o1.x = v4 + excl; o1.y = v5 + excl; o1.z = v6 + excl; o1.w = v7 + excl;
        *reinterpret_cast<f4_t*>(&s[tid * 8])     = o0;
        *reinterpret_cast<f4_t*>(&s[tid * 8 + 4]) = o1;
    }

    // ---- Fixed float4 column per thread across the full 512-float row ----
    const int q = tid & 127;                     // float4 column, 0..127
    const int h = tid >> 7;                      // row parity (wave-pair uniform)
    const int d = q * 4;

    const f4_t f4 = *reinterpret_cast<const f4_t*>(&f[d]);
    const f4_t i4 = *reinterpret_cast<const f4_t*>(&init[b * DZ + d]);

    __syncthreads();

    // ---- Stream 128 contiguous rows; each wave store = 1 KB contiguous ----
    float* outp = out + ((size_t)(g0 + h) * DZ + d);
#pragma unroll 8
    for (int iter = 0; iter < RPB / 2; ++iter) {
        const float st = s[t0 + iter * 2 + h];   // wave-uniform LDS broadcast
        f4_t o;
        o.x = i4.x + f4.x * st;
        o.y = i4.y + f4.y * st;
        o.z = i4.z + f4.z * st;
        o.w = i4.w + f4.w * st;
        *reinterpret_cast<f4_t*>(outp) = o;
        outp += 2 * DZ;
    }
}

extern "C" void kernel_launch(void* const* d_in, const int* in_sizes, int n_in,
                              void* d_out, int out_size, void* d_ws, size_t ws_size,
                              hipStream_t stream) {
    const float* t_in = (const float*)d_in[0];  // (B,T,1) -> (B,T)
    const float* init = (const float*)d_in[1];  // (B,DZ)
    const float* f    = (const float*)d_in[2];  // (1,DZ) -> (DZ)
    float* out        = (float*)d_out;          // (B,T,DZ)

    lts_kernel<<<dim3(NBLOCKS), dim3(256), 0, stream>>>(t_in, init, f, out);
}